// Round 12
// baseline (376.689 us; speedup 1.0000x reference)
//
#include <hip/hip_runtime.h>

#define NN 2048
#define WW 32
#define DD 512
#define MS 512
#define TGTM 1536
#define KSH 14           // 2^14 > union_max^2 -> exact rational order
#define KMAX16 16384u
#define CB 256           // cooperative blocks (1/CU)
#define CT 1024
#define GT (CB*CT)
#define OUTF4 393216     // (2*MS*MS + NN*MS) floats / 4

typedef unsigned long long ull;
typedef unsigned short u16;

__device__ __forceinline__ void atomicMin64(ull* p, ull v){
  ull old = *p;
  while (v < old){
    ull assumed = old;
    old = atomicCAS(p, assumed, v);
    if (old == assumed) break;
  }
}
__device__ __forceinline__ unsigned uf_find(unsigned* par, unsigned x){
  while (true){
    unsigned p = par[x];
    if (p == x) return x;
    unsigned g = par[p];
    if (g == p) return p;
    par[x] = g;
    x = g;
  }
}
__device__ __forceinline__ void uf_union(unsigned* par, unsigned x, unsigned y){
  while (true){
    unsigned rx = uf_find(par, x), ry = uf_find(par, y);
    if (rx == ry) return;
    if (rx > ry){ unsigned tm = rx; rx = ry; ry = tm; }
    if (atomicCAS(&par[ry], ry, rx) == ry) return;
    x = rx; y = ry;
  }
}
__device__ __forceinline__ unsigned block_scan_incl(unsigned v, unsigned* partials, int t){
  int lane = t & 63, wv = t >> 6;
  unsigned x = v;
  #pragma unroll
  for (int off = 1; off < 64; off <<= 1){
    unsigned n = __shfl_up(x, off, 64);
    if (lane >= off) x += n;
  }
  __syncthreads();
  if (lane == 63) partials[wv] = x;
  __syncthreads();
  if (wv == 0){
    unsigned p = (lane < 16) ? partials[lane] : 0u;
    #pragma unroll
    for (int off = 1; off < 16; off <<= 1){
      unsigned n = __shfl_up(p, off, 64);
      if (lane >= off) p += n;
    }
    if (lane < 16) partials[lane] = p;
  }
  __syncthreads();
  if (wv > 0) x += partials[wv-1];
  return x;
}
__device__ __forceinline__ void gbar(unsigned* cnt, unsigned target, int t){
  __syncthreads();
  if (t == 0){
    __threadfence();
    __hip_atomic_fetch_add(cnt, 1u, __ATOMIC_RELEASE, __HIP_MEMORY_SCOPE_AGENT);
    while (__hip_atomic_load(cnt, __ATOMIC_RELAXED, __HIP_MEMORY_SCOPE_AGENT) < target)
      __builtin_amdgcn_s_sleep(1);
    __threadfence();
  }
  __syncthreads();
}

// ONE kernel: zero-out+bits/deg -> keymat -> Boruvka -> final -> coarseX/A.
__global__ void __launch_bounds__(CT)
k_mega(const float* __restrict__ A, const float* __restrict__ X,
       ull* __restrict__ bits, unsigned* __restrict__ degH,
       u16* __restrict__ keyM, ull* __restrict__ node_best /*[2][NN]*/,
       unsigned* __restrict__ bar,
       unsigned* __restrict__ labels_g, float* __restrict__ scale_g,
       unsigned* __restrict__ offs_g, unsigned* __restrict__ memb_g,
       float* __restrict__ out){
  __shared__ __align__(16) char smem[49408];
  int t = threadIdx.x, b = blockIdx.x;
  unsigned ep = 0;
  float* Xc = out;
  float* Ac = out + MS*MS;
  float* P  = out + 2*MS*MS;

  // un-poison barrier counter (safe: each block CASes before its first arrive)
  if (t == 0) atomicCAS(bar, 0xAAAAAAAAu, 0u);

  // ===== P0: zero out buffer; build bitmasks + per-half degrees =====
  {
    unsigned gid = (unsigned)b*CT + t;
    float4 z4 = make_float4(0.f,0.f,0.f,0.f);
    float4* o4 = (float4*)out;
    for (unsigned idx = gid; idx < OUTF4; idx += GT) o4[idx] = z4;
    unsigned unit = gid >> 2, sub = gid & 3;
    unsigned i = unit >> 5, w = unit & 31;
    const float4* rp = (const float4*)(A + ((size_t)i << 11) + (w << 6) + (sub << 4));
    unsigned m16 = 0;
    #pragma unroll
    for (int k = 0; k < 4; ++k){
      float4 v = rp[k];
      if (v.x > 0.f) m16 |= 1u << (4*k+0);
      if (v.y > 0.f) m16 |= 1u << (4*k+1);
      if (v.z > 0.f) m16 |= 1u << (4*k+2);
      if (v.w > 0.f) m16 |= 1u << (4*k+3);
    }
    ull val = ((ull)m16) << (sub*16);
    val |= __shfl_xor(val, 1);
    val |= __shfl_xor(val, 2);
    if (sub == 0) bits[unit] = val;
    unsigned p = __popc(m16);
    #pragma unroll
    for (int off = 32; off; off >>= 1) p += __shfl_xor(p, off);
    if ((t & 63) == 0) degH[((gid >> 6) & 1)*NN + i] = p;   // wave within one row
  }
  gbar(bar, (++ep)*(unsigned)CB, t);

  // ===== P1: key matrix (u16), 2x2 reg tiles, 4 tiles/block =====
  {
    ull (*bi)[33] = (ull(*)[33])smem;
    ull (*bj)[33] = (ull(*)[33])(smem + 16896);
    unsigned* degi = (unsigned*)(smem + 33792);
    unsigned* degj = (unsigned*)(smem + 34048);
    for (int kk = 0; kk < 4; ++kk){
      int T = b + 256*kk;
      int ib = T >> 5, jb = T & 31;
      __syncthreads();
      for (int idx = t; idx < 2048; idx += CT){
        int r = idx >> 5, w = idx & 31;
        bi[r][w] = bits[(((size_t)(ib*64 + r)) << 5) + w];
        bj[r][w] = bits[(((size_t)(jb*64 + r)) << 5) + w];
      }
      if (t < 64){
        degi[t] = degH[ib*64 + t] + degH[NN + ib*64 + t];
        degj[t] = degH[jb*64 + t] + degH[NN + jb*64 + t];
      }
      __syncthreads();
      int tr = (t >> 5) << 1, tc = (t & 31) << 1;
      unsigned i00=0,i01=0,i10=0,i11=0;
      #pragma unroll 8
      for (int w = 0; w < 32; ++w){
        ull a0 = bi[tr][w], a1 = bi[tr+1][w];
        ull c0 = bj[tc][w], c1 = bj[tc+1][w];
        i00 += (unsigned)__popcll(a0 & c0);
        i01 += (unsigned)__popcll(a0 & c1);
        i10 += (unsigned)__popcll(a1 & c0);
        i11 += (unsigned)__popcll(a1 & c1);
      }
      unsigned d0 = degi[tr], d1 = degi[tr+1], e0 = degj[tc], e1 = degj[tc+1];
      #pragma unroll
      for (int r = 0; r < 2; ++r){
        int i = ib*64 + tr + r;
        unsigned dr = r ? d1 : d0;
        u16 kv[2];
        #pragma unroll
        for (int c = 0; c < 2; ++c){
          int j = jb*64 + tc + c;
          unsigned iv = r ? (c ? i11 : i10) : (c ? i01 : i00);
          unsigned key = 0u;
          if (i != j){
            unsigned bb = dr + (c ? e1 : e0) - iv;
            if (bb) key = ((iv << KSH) + (bb >> 1)) / bb;
          }
          kv[c] = (u16)key;
        }
        *(ushort2*)(keyM + (((size_t)i) << 11) + (jb*64 + tc)) = make_ushort2(kv[0], kv[1]);
      }
    }
  }
  gbar(bar, (++ep)*(unsigned)CB, t);

  // ===== P2: Boruvka rounds (redundant merge, identical state per block) =====
  ull* ed        = (ull*)smem;                    // 16384
  ull* cbest     = (ull*)(smem + 16384);          // 16384
  unsigned* lab  = (unsigned*)(smem + 32768);     // 8192
  unsigned* nxtA = (unsigned*)(smem + 40960);     // 8192
  unsigned* cntS     = (unsigned*)(smem + 49152);
  unsigned* gcntS    = (unsigned*)(smem + 49156);
  unsigned* selS     = (unsigned*)(smem + 49168); // 4 u32
  unsigned* partials = (unsigned*)(smem + 49216); // 16 u32
  ull* rowbest       = (ull*)(smem + 49280);      // 8 u64
  if (t == 0) *cntS = 0;
  for (int i = t; i < NN; i += CT) lab[i] = (unsigned)i;
  __syncthreads();

  for (int round = 0; round < 11; ++round){
    ull* nb = node_best + ((round & 1) ? NN : 0);
    for (int c = t; c < NN; c += CT){ cbest[c] = ~0ull; nxtA[c] = (unsigned)c; }
    if (t < 8) rowbest[t] = ~0ull;
    __syncthreads();
    // best phase: 16 waves, 2 waves per row (half columns each)
    {
      int wv = t >> 6, lane = t & 63;
      int i = b*8 + (wv >> 1);
      int jbase = (wv & 1) << 10;
      unsigned ci = lab[i];
      const u16* row = keyM + ((size_t)i << 11);
      ull best = ~0ull;
      #pragma unroll
      for (int it = 0; it < 4; ++it){
        int j0 = jbase + it*256 + lane*4;
        ushort4 k4 = *(const ushort4*)(row + j0);
        uint4   c4 = *(const uint4*)(lab + j0);
        #pragma unroll
        for (int q = 0; q < 4; ++q){
          int j = j0 + q;
          unsigned key = (q==0)?k4.x:(q==1)?k4.y:(q==2)?k4.z:k4.w;
          unsigned cj  = (q==0)?c4.x:(q==1)?c4.y:(q==2)?c4.z:c4.w;
          if (j == i || cj == ci) continue;
          unsigned kp = KMAX16 - key;
          unsigned a  = (i < j) ? (unsigned)i : (unsigned)j;
          unsigned b2 = (i < j) ? (unsigned)j : (unsigned)i;
          ull v = (((ull)kp) << 22) | (((ull)a) << 11) | b2;
          if (v < best) best = v;
        }
      }
      #pragma unroll
      for (int off = 32; off; off >>= 1){
        ull o = __shfl_xor(best, off);
        if (o < best) best = o;
      }
      if (lane == 0) atomicMin64(&rowbest[wv >> 1], best);
    }
    __syncthreads();
    if (t < 8) nb[b*8 + t] = rowbest[t];
    gbar(bar, (++ep)*(unsigned)CB, t);
    // merge (all blocks, identical): scatter, union+collect, relabel
    for (int i = t; i < NN; i += CT) atomicMin64(&cbest[lab[i]], nb[i]);
    __syncthreads();
    for (int c = t; c < NN; c += CT){
      ull v = cbest[c];
      if (v == ~0ull) continue;
      unsigned a = (unsigned)((v >> 11) & 2047u), b2 = (unsigned)(v & 2047u);
      unsigned la = lab[a], lb = lab[b2];
      if (la == lb) continue;
      unsigned other = (la == (unsigned)c) ? lb : la;
      if (!(cbest[other] == v && other < (unsigned)c)){
        unsigned idx = atomicAdd(cntS, 1u);
        if (idx < (unsigned)NN) ed[idx] = v;
      }
      uf_union(nxtA, la, lb);
    }
    __syncthreads();
    for (int i = t; i < NN; i += CT) lab[i] = uf_find(nxtA, lab[i]);
    __syncthreads();
    if (*cntS >= (unsigned)(NN-1)) break;
  }

  // ===== P3: final phase (block 0 only) =====
  if (b == 0){
    unsigned cnt = *cntS; if (cnt > (unsigned)NN) cnt = NN;
    unsigned* h1 = lab;
    unsigned* h2 = lab + 256;
    for (int k = t; k < 129+256; k += CT) if (k < 129 || k >= 256) lab[k] = 0u;
    if (t < 128) h2[t] = 0u;
    if (t == 0){ selS[0] = 128u; selS[1] = 1u; selS[2] = 127u; selS[3] = 1u; *gcntS = 0u; }
    __syncthreads();
    for (int e = t; e < (int)cnt; e += CT) atomicAdd(&h1[(unsigned)(ed[e] >> 29)], 1u);
    __syncthreads();
    if (t == 0){
      unsigned c = 0;
      for (unsigned bk = 0; bk <= 128; ++bk){
        if (c + h1[bk] >= (unsigned)TGTM){ selS[0] = bk; selS[1] = (unsigned)TGTM - c; break; }
        c += h1[bk];
      }
    }
    __syncthreads();
    unsigned B1 = selS[0], r1 = selS[1];
    for (int e = t; e < (int)cnt; e += CT){
      ull v = ed[e];
      if ((unsigned)(v >> 29) == B1) atomicAdd(&h2[(unsigned)((v >> 22) & 127u)], 1u);
    }
    __syncthreads();
    if (t == 0){
      unsigned c = 0;
      for (unsigned bk = 0; bk < 128; ++bk){
        if (c + h2[bk] >= r1){ selS[2] = bk; selS[3] = r1 - c; break; }
        c += h2[bk];
      }
    }
    __syncthreads();
    unsigned B2 = selS[2], r2 = selS[3];
    unsigned kpSel = (B1 << 7) | B2;
    ull* glist = cbest;
    for (int e = t; e < (int)cnt; e += CT){
      ull v = ed[e];
      if ((unsigned)(v >> 22) == kpSel){
        unsigned idx = atomicAdd(gcntS, 1u);
        glist[idx] = v;
      }
    }
    for (int c = t; c < NN; c += CT) nxtA[c] = (unsigned)c;
    __syncthreads();
    unsigned gc = *gcntS;
    for (int e = t; e < (int)cnt; e += CT){
      ull v = ed[e];
      unsigned kp = (unsigned)(v >> 22);
      bool sel;
      if (kp < kpSel) sel = true;
      else if (kp > kpSel) sel = false;
      else {
        unsigned r = 0;
        for (unsigned j = 0; j < gc; ++j) r += (glist[j] < v) ? 1u : 0u;
        sel = (r < r2);
      }
      if (sel){
        unsigned a = (unsigned)((v >> 11) & 2047u), b2 = (unsigned)(v & 2047u);
        uf_union(nxtA, a, b2);
      }
    }
    __syncthreads();
    for (int i = t; i < NN; i += CT) lab[i] = uf_find(nxtA, (unsigned)i);
    __syncthreads();
    unsigned* plab  = (unsigned*)ed;
    unsigned* sizes = (unsigned*)cbest;
    int i0 = 2*t, i1 = 2*t + 1;
    unsigned f0 = (lab[i0] == (unsigned)i0) ? 1u : 0u;
    unsigned f1 = (lab[i1] == (unsigned)i1) ? 1u : 0u;
    unsigned s = f0 + f1;
    unsigned incl = block_scan_incl(s, partials, t);
    plab[i0] = incl - s; plab[i1] = incl - s + f0;
    for (int c = t; c < MS; c += CT) sizes[c] = 0u;
    __syncthreads();
    for (int i = t; i < NN; i += CT){
      unsigned L = plab[lab[i]];
      labels_g[i] = L;
      if (L < (unsigned)MS) atomicAdd(&sizes[L], 1u);
    }
    __syncthreads();
    for (int c = t; c < MS; c += CT) scale_g[c] = 1.0f / sqrtf((float)sizes[c] + 1e-10f);
    unsigned* off_l  = nxtA;
    unsigned* cursor = nxtA + 1024;
    unsigned my = (t < MS) ? sizes[t] : 0u;
    unsigned incl2 = block_scan_incl(my, partials, t);
    if (t < MS){
      unsigned ex = incl2 - my;
      off_l[t] = ex; offs_g[t] = ex;
    }
    if (t == 0) offs_g[MS] = (unsigned)NN;
    __syncthreads();
    for (int c = t; c < MS; c += CT) cursor[c] = off_l[c];
    __syncthreads();
    for (int i = t; i < NN; i += CT){
      unsigned L = plab[lab[i]];
      unsigned pos = atomicAdd(&cursor[L], 1u);
      memb_g[pos] = (unsigned)i;
    }
    for (int i = t; i < NN; i += CT){
      unsigned L = plab[lab[i]];
      P[((size_t)i << 9) + L] = 1.0f / sqrtf((float)sizes[L] + 1e-10f);
    }
  }
  gbar(bar, (++ep)*(unsigned)CB, t);

  // ===== P4: coarse X and A (all blocks; staged offs/labels/scale) =====
  {
    unsigned* labS   = (unsigned*)smem;           // 8192
    float*    scaleS = (float*)(smem + 8192);     // 2048
    unsigned* offsS  = (unsigned*)(smem + 10240); // 2052
    float*    rowA   = (float*)(smem + 12544);    // 2048
    float*    spadX  = (float*)(smem + 14592);    // 2048
    unsigned* mlistX = (unsigned*)(smem + 16640); // 512
    unsigned* mlistA = (unsigned*)(smem + 17152); // 256
    for (int i = t; i < NN; i += CT) labS[i] = labels_g[i];
    for (int c = t; c < MS; c += CT) scaleS[c] = scale_g[c];
    for (int c = t; c <= MS; c += CT) offsS[c] = offs_g[c];
    __syncthreads();
    // coarseX: items (c, slice of 128 members); 512 d-threads x 2 member-halves
    for (int item = b; item < MS*16; item += CB){
      int c = item >> 4, sl = item & 15;
      unsigned o0 = offsS[c], e = offsS[c+1];
      unsigned o = o0 + (unsigned)sl*128u;
      if (o >= e) continue;                      // block-uniform
      int nm = (int)min(128u, e - o);
      if (t < nm) mlistX[t] = memb_g[o + t];
      __syncthreads();
      int d = t & 511, h = t >> 9;
      int nm2 = nm >> 1;
      int lo = h ? nm2 : 0, hi = h ? nm : nm2;
      float a0=0.f,a1=0.f,a2=0.f,a3=0.f,a4=0.f,a5=0.f,a6=0.f,a7=0.f;
      int k = lo;
      for (; k + 8 <= hi; k += 8){
        a0 += X[((size_t)mlistX[k+0] << 9) + d];
        a1 += X[((size_t)mlistX[k+1] << 9) + d];
        a2 += X[((size_t)mlistX[k+2] << 9) + d];
        a3 += X[((size_t)mlistX[k+3] << 9) + d];
        a4 += X[((size_t)mlistX[k+4] << 9) + d];
        a5 += X[((size_t)mlistX[k+5] << 9) + d];
        a6 += X[((size_t)mlistX[k+6] << 9) + d];
        a7 += X[((size_t)mlistX[k+7] << 9) + d];
      }
      for (; k < hi; ++k) a0 += X[((size_t)mlistX[k] << 9) + d];
      float acc = ((a0+a1)+(a2+a3)) + ((a4+a5)+(a6+a7));
      if (h == 1) spadX[d] = acc;
      __syncthreads();
      if (h == 0){
        float tot = (acc + spadX[d]) * scaleS[c];
        if (e - o0 <= 128u) Xc[((size_t)c << 9) + d] = tot;
        else atomicAdd(&Xc[((size_t)c << 9) + d], tot);
      }
      __syncthreads();
    }
    // coarseA: items (c, slice of 64 members); LDS histogram
    for (int item = b; item < MS*32; item += CB){
      int c = item >> 5, sl = item & 31;
      unsigned o0 = offsS[c], e = offsS[c+1];
      unsigned o = o0 + (unsigned)sl*64u;
      if (o >= e) continue;                      // block-uniform
      int nm = (int)min(64u, e - o);
      if (t < MS) rowA[t] = 0.0f;
      if (t < nm) mlistA[t] = memb_g[o + t];
      __syncthreads();
      for (int idx = t; idx < nm*WW; idx += CT){
        unsigned m = mlistA[idx >> 5];
        int w = idx & 31;
        ull word = bits[((size_t)m << 5) + w];
        while (word){
          int bb = __ffsll((long long)word) - 1;
          unsigned j = (unsigned)(w*64 + bb);
          atomicAdd(&rowA[labS[j]], 1.0f);
          word &= word - 1ull;
        }
      }
      __syncthreads();
      if (t < MS){
        float v = rowA[t];
        float sc = scaleS[c];
        bool single = (e - o0) <= 64u;
        if (single) Ac[((size_t)c << 9) + t] = v * sc * scaleS[t];
        else if (v != 0.0f) atomicAdd(&Ac[((size_t)c << 9) + t], v * sc * scaleS[t]);
      }
      __syncthreads();
    }
  }
}

extern "C" void kernel_launch(void* const* d_in, const int* in_sizes, int n_in,
                              void* d_out, int out_size, void* d_ws, size_t ws_size,
                              hipStream_t stream) {
  const float* X = (const float*)d_in[0];
  const float* A = (const float*)d_in[1];
  float* out = (float*)d_out;
  char* ws = (char*)d_ws;
  ull*      bits     = (ull*)     (ws + 0x000000);  // 512 KB
  unsigned* degH     = (unsigned*)(ws + 0x080000);  // 16 KB (2 halves per row)
  ull*      nodebest = (ull*)     (ws + 0x084000);  // 32 KB double-buffered
  unsigned* labels   = (unsigned*)(ws + 0x08C000);  // 8 KB
  float*    scale    = (float*)   (ws + 0x08E000);  // 2 KB
  unsigned* offs     = (unsigned*)(ws + 0x08E800);  // 2052 B
  unsigned* memb     = (unsigned*)(ws + 0x08F800);  // 8 KB
  unsigned* bar      = (unsigned*)(ws + 0x098000);  // 4 B (CAS-unpoisoned in-kernel)
  u16*      keyM     = (u16*)     (ws + 0x0A0000);  // 8 MB

  void* args[] = { (void*)&A, (void*)&X, (void*)&bits, (void*)&degH,
                   (void*)&keyM, (void*)&nodebest, (void*)&bar,
                   (void*)&labels, (void*)&scale, (void*)&offs, (void*)&memb,
                   (void*)&out };
  hipLaunchCooperativeKernel((void*)k_mega, dim3(CB), dim3(CT), args, 0, stream);
}

// Round 13
// 250.035 us; speedup vs baseline: 1.5065x; 1.5065x over previous
//
#include <hip/hip_runtime.h>

#define NN 2048
#define WW 32
#define DD 512
#define MS 512
#define TGTM 1536
#define KSH 14           // 2^14 > union_max^2 -> exact rational order
#define KMAX16 16384u
#define CB 128           // cooperative blocks (1 row per wave: 128*16 = 2048)
#define CT 1024
#define ASL 64           // coarseA members per slice
#define MSL 128          // coarseX members per slice
#define OUTF4 393216     // (2*MS*MS + NN*MS) floats / 4

typedef unsigned long long ull;
typedef unsigned short u16;

__device__ __forceinline__ void atomicMin64(ull* p, ull v){
  ull old = *p;
  while (v < old){
    ull assumed = old;
    old = atomicCAS(p, assumed, v);
    if (old == assumed) break;
  }
}
__device__ __forceinline__ unsigned uf_find(unsigned* par, unsigned x){
  while (true){
    unsigned p = par[x];
    if (p == x) return x;
    unsigned g = par[p];
    if (g == p) return p;
    par[x] = g;
    x = g;
  }
}
__device__ __forceinline__ void uf_union(unsigned* par, unsigned x, unsigned y){
  while (true){
    unsigned rx = uf_find(par, x), ry = uf_find(par, y);
    if (rx == ry) return;
    if (rx > ry){ unsigned tm = rx; rx = ry; ry = tm; }
    if (atomicCAS(&par[ry], ry, rx) == ry) return;
    x = rx; y = ry;
  }
}
__device__ __forceinline__ unsigned block_scan_incl(unsigned v, unsigned* partials, int t){
  int lane = t & 63, wv = t >> 6;
  unsigned x = v;
  #pragma unroll
  for (int off = 1; off < 64; off <<= 1){
    unsigned n = __shfl_up(x, off, 64);
    if (lane >= off) x += n;
  }
  __syncthreads();
  if (lane == 63) partials[wv] = x;
  __syncthreads();
  if (wv == 0){
    unsigned p = (lane < 16) ? partials[lane] : 0u;
    #pragma unroll
    for (int off = 1; off < 16; off <<= 1){
      unsigned n = __shfl_up(p, off, 64);
      if (lane >= off) p += n;
    }
    if (lane < 16) partials[lane] = p;
  }
  __syncthreads();
  if (wv > 0) x += partials[wv-1];
  return x;
}
__device__ __forceinline__ void gbar(unsigned* cnt, unsigned target, int t){
  __syncthreads();
  if (t == 0){
    __threadfence();
    __hip_atomic_fetch_add(cnt, 1u, __ATOMIC_RELEASE, __HIP_MEMORY_SCOPE_AGENT);
    while (__hip_atomic_load(cnt, __ATOMIC_RELAXED, __HIP_MEMORY_SCOPE_AGENT) < target)
      __builtin_amdgcn_s_sleep(1);
    __threadfence();
  }
  __syncthreads();
}

// Build bitmasks + degrees; also zero the whole out buffer and un-poison bar.
__global__ void k_build(const float* __restrict__ A, ull* __restrict__ bits,
                        unsigned* __restrict__ deg, unsigned* __restrict__ bar,
                        float* __restrict__ out){
  int gid = blockIdx.x*blockDim.x + threadIdx.x;   // 65536 threads
  // zero Xc+Ac+P (6 MB), grid-stride float4
  float4 z4 = make_float4(0.f,0.f,0.f,0.f);
  float4* o4 = (float4*)out;
  for (unsigned idx = (unsigned)gid; idx < OUTF4; idx += 65536u) o4[idx] = z4;
  if (threadIdx.x == 0) atomicCAS(bar, 0xAAAAAAAAu, 0u);   // un-poison barrier counter
  int i = gid >> 5, w = gid & 31;
  const float4* row = (const float4*)(A + ((size_t)i << 11) + (w << 6));
  ull m = 0ull;
  #pragma unroll
  for (int k = 0; k < 16; ++k){
    float4 v = row[k];
    if (v.x > 0.0f) m |= (1ull << (4*k+0));
    if (v.y > 0.0f) m |= (1ull << (4*k+1));
    if (v.z > 0.0f) m |= (1ull << (4*k+2));
    if (v.w > 0.0f) m |= (1ull << (4*k+3));
  }
  bits[((size_t)i << 5) + w] = m;
  unsigned p = (unsigned)__popcll(m);
  #pragma unroll
  for (int off = 16; off; off >>= 1) p += __shfl_xor(p, off, 32);
  if (w == 0) deg[i] = p;
}

// Key matrix (u16), 4x4 register-tiled (R11 verbatim).
__global__ void k_keymat(const ull* __restrict__ bits,
                         const unsigned* __restrict__ deg, u16* __restrict__ keyM){
  __shared__ ull bi[64][33];
  __shared__ ull bj[64][33];
  __shared__ unsigned degi[64], degj[64];
  int ib = blockIdx.x, jb = blockIdx.y;
  int t = threadIdx.x;
  for (int idx = t; idx < 64*32; idx += 256){
    int r = idx >> 5, w = idx & 31;
    bi[r][w] = bits[(((size_t)(ib*64 + r)) << 5) + w];
    bj[r][w] = bits[(((size_t)(jb*64 + r)) << 5) + w];
  }
  if (t < 64){ degi[t] = deg[ib*64 + t]; degj[t] = deg[jb*64 + t]; }
  __syncthreads();
  int tr = (t >> 4) << 2;
  int tc = (t & 15) << 2;
  unsigned inter[4][4];
  #pragma unroll
  for (int r = 0; r < 4; ++r)
    #pragma unroll
    for (int c = 0; c < 4; ++c) inter[r][c] = 0u;
  #pragma unroll 8
  for (int w = 0; w < 32; ++w){
    ull a0 = bi[tr+0][w], a1 = bi[tr+1][w], a2 = bi[tr+2][w], a3 = bi[tr+3][w];
    ull b0 = bj[tc+0][w], b1 = bj[tc+1][w], b2 = bj[tc+2][w], b3 = bj[tc+3][w];
    inter[0][0] += (unsigned)__popcll(a0 & b0);
    inter[0][1] += (unsigned)__popcll(a0 & b1);
    inter[0][2] += (unsigned)__popcll(a0 & b2);
    inter[0][3] += (unsigned)__popcll(a0 & b3);
    inter[1][0] += (unsigned)__popcll(a1 & b0);
    inter[1][1] += (unsigned)__popcll(a1 & b1);
    inter[1][2] += (unsigned)__popcll(a1 & b2);
    inter[1][3] += (unsigned)__popcll(a1 & b3);
    inter[2][0] += (unsigned)__popcll(a2 & b0);
    inter[2][1] += (unsigned)__popcll(a2 & b1);
    inter[2][2] += (unsigned)__popcll(a2 & b2);
    inter[2][3] += (unsigned)__popcll(a2 & b3);
    inter[3][0] += (unsigned)__popcll(a3 & b0);
    inter[3][1] += (unsigned)__popcll(a3 & b1);
    inter[3][2] += (unsigned)__popcll(a3 & b2);
    inter[3][3] += (unsigned)__popcll(a3 & b3);
  }
  #pragma unroll
  for (int r = 0; r < 4; ++r){
    int i = ib*64 + tr + r;
    u16 kv[4];
    #pragma unroll
    for (int c = 0; c < 4; ++c){
      int j = jb*64 + tc + c;
      unsigned key = 0u;
      if (i != j){
        unsigned iv = inter[r][c];
        unsigned b = degi[tr+r] + degj[tc+c] - iv;
        if (b != 0u){
          unsigned num = (iv << KSH) + (b >> 1);
          key = num / b;
        }
      }
      kv[c] = (u16)key;
    }
    *(ushort4*)(keyM + (((size_t)i) << 11) + (jb*64 + tc)) =
        make_ushort4(kv[0], kv[1], kv[2], kv[3]);
  }
}

// Fused Boruvka + finalization (R11 verbatim): one custom grid barrier + 3 LDS
// barriers per round, lock-free UF merge redundant per block; radix-select final.
__global__ void __launch_bounds__(CT)
k_boruvka(const u16* __restrict__ keyM, ull* __restrict__ node_best /*[2][NN]*/,
          unsigned* __restrict__ bar,
          unsigned* __restrict__ labels_g, float* __restrict__ scale_g,
          unsigned* __restrict__ offs_g, unsigned* __restrict__ memb_g,
          float* __restrict__ P){
  __shared__ ull ed[NN];
  __shared__ ull cbest[NN];
  __shared__ alignas(16) unsigned lab[NN];
  __shared__ unsigned nxtA[NN];
  __shared__ unsigned partials[16];
  __shared__ unsigned selS[4];
  __shared__ unsigned gcntS;
  __shared__ unsigned cntS;
  int t = threadIdx.x;
  int b = blockIdx.x;
  if (t == 0) cntS = 0;
  for (int i = t; i < NN; i += CT) lab[i] = (unsigned)i;
  __syncthreads();

  for (int round = 0; round < 11; ++round){
    ull* nb = node_best + ((round & 1) ? NN : 0);
    for (int c = t; c < NN; c += CT){ cbest[c] = ~0ull; nxtA[c] = (unsigned)c; }
    {
      int i = b*(CT/64) + (t >> 6);
      int lane = t & 63;
      unsigned ci = lab[i];
      const u16* row = keyM + ((size_t)i << 11);
      ull best = ~0ull;
      #pragma unroll
      for (int it = 0; it < 8; ++it){
        int j0 = it*256 + lane*4;
        ushort4 k4 = *(const ushort4*)(row + j0);
        uint4   c4 = *(const uint4*)(lab + j0);
        #pragma unroll
        for (int q = 0; q < 4; ++q){
          int j = j0 + q;
          unsigned key = (q==0)?k4.x:(q==1)?k4.y:(q==2)?k4.z:k4.w;
          unsigned cj  = (q==0)?c4.x:(q==1)?c4.y:(q==2)?c4.z:c4.w;
          if (j == i || cj == ci) continue;
          unsigned kp = KMAX16 - key;
          unsigned a  = (i < j) ? (unsigned)i : (unsigned)j;
          unsigned b2 = (i < j) ? (unsigned)j : (unsigned)i;
          ull v = (((ull)kp) << 22) | (((ull)a) << 11) | b2;
          if (v < best) best = v;
        }
      }
      for (int off = 32; off; off >>= 1){
        ull o = __shfl_xor(best, off);
        if (o < best) best = o;
      }
      if (lane == 0) nb[i] = best;
    }
    gbar(bar, (unsigned)(round + 1) * (unsigned)CB, t);
    for (int i = t; i < NN; i += CT) atomicMin64(&cbest[lab[i]], nb[i]);
    __syncthreads();
    for (int c = t; c < NN; c += CT){
      ull v = cbest[c];
      if (v == ~0ull) continue;
      unsigned a = (unsigned)((v >> 11) & 2047u), b2 = (unsigned)(v & 2047u);
      unsigned la = lab[a], lb = lab[b2];
      if (la == lb) continue;
      unsigned other = (la == (unsigned)c) ? lb : la;
      if (!(cbest[other] == v && other < (unsigned)c)){
        unsigned idx = atomicAdd(&cntS, 1u);
        if (idx < (unsigned)NN) ed[idx] = v;
      }
      uf_union(nxtA, la, lb);
    }
    __syncthreads();
    for (int i = t; i < NN; i += CT) lab[i] = uf_find(nxtA, lab[i]);
    __syncthreads();
    if (cntS >= (unsigned)(NN-1)) break;
  }
  if (b != 0) return;

  // final phase (block 0 only)
  unsigned cnt = cntS; if (cnt > (unsigned)NN) cnt = NN;
  unsigned* h1 = lab;
  unsigned* h2 = lab + 256;
  for (int k = t; k < 129+256; k += CT) if (k < 129 || k >= 256) lab[k] = 0u;
  if (t < 128) h2[t] = 0u;
  if (t == 0){ selS[0] = 128u; selS[1] = 1u; selS[2] = 127u; selS[3] = 1u; gcntS = 0u; }
  __syncthreads();
  for (int e = t; e < (int)cnt; e += CT) atomicAdd(&h1[(unsigned)(ed[e] >> 29)], 1u);
  __syncthreads();
  if (t == 0){
    unsigned c = 0;
    for (unsigned bk = 0; bk <= 128; ++bk){
      if (c + h1[bk] >= (unsigned)TGTM){ selS[0] = bk; selS[1] = (unsigned)TGTM - c; break; }
      c += h1[bk];
    }
  }
  __syncthreads();
  unsigned B1 = selS[0], r1 = selS[1];
  for (int e = t; e < (int)cnt; e += CT){
    ull v = ed[e];
    if ((unsigned)(v >> 29) == B1) atomicAdd(&h2[(unsigned)((v >> 22) & 127u)], 1u);
  }
  __syncthreads();
  if (t == 0){
    unsigned c = 0;
    for (unsigned bk = 0; bk < 128; ++bk){
      if (c + h2[bk] >= r1){ selS[2] = bk; selS[3] = r1 - c; break; }
      c += h2[bk];
    }
  }
  __syncthreads();
  unsigned B2 = selS[2], r2 = selS[3];
  unsigned kpSel = (B1 << 7) | B2;
  ull* glist = cbest;
  for (int e = t; e < (int)cnt; e += CT){
    ull v = ed[e];
    if ((unsigned)(v >> 22) == kpSel){
      unsigned idx = atomicAdd(&gcntS, 1u);
      glist[idx] = v;
    }
  }
  for (int c = t; c < NN; c += CT) nxtA[c] = (unsigned)c;
  __syncthreads();
  unsigned gc = gcntS;
  for (int e = t; e < (int)cnt; e += CT){
    ull v = ed[e];
    unsigned kp = (unsigned)(v >> 22);
    bool sel;
    if (kp < kpSel) sel = true;
    else if (kp > kpSel) sel = false;
    else {
      unsigned r = 0;
      for (unsigned j = 0; j < gc; ++j) r += (glist[j] < v) ? 1u : 0u;
      sel = (r < r2);
    }
    if (sel){
      unsigned a = (unsigned)((v >> 11) & 2047u), b2 = (unsigned)(v & 2047u);
      uf_union(nxtA, a, b2);
    }
  }
  __syncthreads();
  for (int i = t; i < NN; i += CT) lab[i] = uf_find(nxtA, (unsigned)i);
  __syncthreads();
  unsigned* plab  = (unsigned*)ed;
  unsigned* sizes = (unsigned*)cbest;
  int i0 = 2*t, i1 = 2*t + 1;
  unsigned f0 = (lab[i0] == (unsigned)i0) ? 1u : 0u;
  unsigned f1 = (lab[i1] == (unsigned)i1) ? 1u : 0u;
  unsigned s = f0 + f1;
  unsigned incl = block_scan_incl(s, partials, t);
  plab[i0] = incl - s; plab[i1] = incl - s + f0;
  for (int c = t; c < MS; c += CT) sizes[c] = 0u;
  __syncthreads();
  for (int i = t; i < NN; i += CT){
    unsigned L = plab[lab[i]];
    labels_g[i] = L;
    if (L < (unsigned)MS) atomicAdd(&sizes[L], 1u);
  }
  __syncthreads();
  for (int c = t; c < MS; c += CT) scale_g[c] = 1.0f / sqrtf((float)sizes[c] + 1e-10f);
  unsigned* off_l  = nxtA;
  unsigned* cursor = nxtA + 1024;
  unsigned my = (t < MS) ? sizes[t] : 0u;
  unsigned incl2 = block_scan_incl(my, partials, t);
  if (t < MS){
    unsigned ex = incl2 - my;
    off_l[t] = ex; offs_g[t] = ex;
  }
  if (t == 0) offs_g[MS] = (unsigned)NN;
  __syncthreads();
  for (int c = t; c < MS; c += CT) cursor[c] = off_l[c];
  __syncthreads();
  for (int i = t; i < NN; i += CT){
    unsigned L = plab[lab[i]];
    unsigned pos = atomicAdd(&cursor[L], 1u);
    memb_g[pos] = (unsigned)i;
  }
  for (int i = t; i < NN; i += CT){
    unsigned L = plab[lab[i]];
    P[((size_t)i << 9) + L] = 1.0f / sqrtf((float)sizes[L] + 1e-10f);
  }
}

// Fused coarse: grid (MS, 57). y<32: X item (dtile=y>>4 of 256 cols, member
// slice y&15 of 128). y>=32: A item (member slice y-32 of 64). 256 threads.
__global__ void k_coarse(const float* __restrict__ X, const ull* __restrict__ bits,
                         const unsigned* __restrict__ labels,
                         const unsigned* __restrict__ offs, const unsigned* __restrict__ memb,
                         const float* __restrict__ scale,
                         float* __restrict__ Xc, float* __restrict__ Ac){
  int c = blockIdx.x, y = blockIdx.y, t = threadIdx.x;
  unsigned o0 = offs[c], e = offs[c+1];
  if (y < 32){
    __shared__ unsigned mlist[MSL];
    int dtile = y >> 4, sl = y & 15;
    unsigned o = o0 + (unsigned)sl*(unsigned)MSL;
    if (o >= e) return;                       // uniform per block
    int nm = (int)min((unsigned)MSL, e - o);
    if (t < nm) mlist[t] = memb[o + t];
    __syncthreads();
    int d = dtile*256 + t;
    float a0=0.f,a1=0.f,a2=0.f,a3=0.f,a4=0.f,a5=0.f,a6=0.f,a7=0.f;
    int k = 0;
    for (; k + 8 <= nm; k += 8){
      a0 += X[((size_t)mlist[k+0] << 9) + d];
      a1 += X[((size_t)mlist[k+1] << 9) + d];
      a2 += X[((size_t)mlist[k+2] << 9) + d];
      a3 += X[((size_t)mlist[k+3] << 9) + d];
      a4 += X[((size_t)mlist[k+4] << 9) + d];
      a5 += X[((size_t)mlist[k+5] << 9) + d];
      a6 += X[((size_t)mlist[k+6] << 9) + d];
      a7 += X[((size_t)mlist[k+7] << 9) + d];
    }
    for (; k < nm; ++k) a0 += X[((size_t)mlist[k] << 9) + d];
    float acc = (((a0+a1)+(a2+a3)) + ((a4+a5)+(a6+a7))) * scale[c];
    if (e - o0 <= (unsigned)MSL) Xc[((size_t)c << 9) + d] = acc;
    else atomicAdd(&Xc[((size_t)c << 9) + d], acc);
  } else {
    __shared__ float row[MS];
    __shared__ unsigned labS[NN];
    __shared__ unsigned mlistA[ASL];
    int sl = y - 32;
    unsigned o = o0 + (unsigned)sl*(unsigned)ASL;
    if (o >= e) return;                       // uniform per block
    int nm = (int)min((unsigned)ASL, e - o);
    for (int j = t; j < MS; j += 256) row[j] = 0.0f;
    for (int i = t; i < NN; i += 256) labS[i] = labels[i];
    if (t < nm) mlistA[t] = memb[o + t];
    __syncthreads();
    for (int idx = t; idx < nm*WW; idx += 256){
      unsigned m = mlistA[idx >> 5];
      int w = idx & 31;
      ull word = bits[((size_t)m << 5) + w];
      while (word){
        int bb = __ffsll((long long)word) - 1;
        unsigned j = (unsigned)(w*64 + bb);
        atomicAdd(&row[labS[j]], 1.0f);       // LDS atomic
        word &= word - 1ull;
      }
    }
    __syncthreads();
    float sc = scale[c];
    bool single = (e - o0) <= (unsigned)ASL;
    if (single){
      for (int j = t; j < MS; j += 256)
        Ac[((size_t)c << 9) + j] = row[j] * sc * scale[j];
    } else {
      for (int j = t; j < MS; j += 256){
        float v = row[j];
        if (v != 0.0f) atomicAdd(&Ac[((size_t)c << 9) + j], v * sc * scale[j]);
      }
    }
  }
}

extern "C" void kernel_launch(void* const* d_in, const int* in_sizes, int n_in,
                              void* d_out, int out_size, void* d_ws, size_t ws_size,
                              hipStream_t stream) {
  const float* X = (const float*)d_in[0];
  const float* A = (const float*)d_in[1];
  float* out = (float*)d_out;
  char* ws = (char*)d_ws;
  ull*      bits     = (ull*)     (ws + 0x000000);  // 512 KB
  unsigned* deg      = (unsigned*)(ws + 0x080000);  // 8 KB (dead after keymat)
  ull*      nodebest = (ull*)     (ws + 0x084000);  // 32 KB double-buffered
  unsigned* labels   = (unsigned*)(ws + 0x08D000);  // 8 KB
  float*    scale    = (float*)   (ws + 0x08F000);  // 2 KB
  unsigned* bar      = (unsigned*)(ws + 0x08F800);  // 4 B (CAS-unpoisoned in k_build)
  unsigned* memb     = (unsigned*)(ws + 0x084000);  // overlays nodebest (8 KB)
  unsigned* offs     = (unsigned*)(ws + 0x080000);  // overlays deg (2052 B)
  u16*      keyM     = (u16*)     (ws + 0x090000);  // 8 MB

  float* Xc = out;
  float* Ac = out + MS*MS;
  float* P  = out + 2*MS*MS;

  k_build<<<(NN*WW)/256, 256, 0, stream>>>(A, bits, deg, bar, out);
  k_keymat<<<dim3(NN/64, NN/64), 256, 0, stream>>>(bits, deg, keyM);

  void* args[] = { (void*)&keyM, (void*)&nodebest, (void*)&bar,
                   (void*)&labels, (void*)&scale, (void*)&offs, (void*)&memb, (void*)&P };
  hipLaunchCooperativeKernel((void*)k_boruvka, dim3(CB), dim3(CT), args, 0, stream);

  k_coarse<<<dim3(MS, 57), 256, 0, stream>>>(X, bits, labels, offs, memb, scale, Xc, Ac);
}